// Round 3
// baseline (528.966 us; speedup 1.0000x reference)
//
#include <hip/hip_runtime.h>
#include <hip/hip_bf16.h>
#include <cstdint>

// MinGRU: g=sigmoid(xWg^T+bg), c=tanh(xWh^T+bh), h_t = g*h_{t-1} + (1-g)*c
// B=8, L=4096, D=1024.  M = B*L = 32768, K = E = 1024.
//
// R6 == R5 resubmit (R5 bench was a container-acquisition failure, no data).
//  - 512-thread blocks, 8 waves (2x4), each wave owns 64x32 per output array:
//    acc = 64 VGPR (was 128) -> __launch_bounds__(512,4) -> 16 waves/CU (was 8).
//  - epilogue in 32-row slabs (= one scan chunk): g+c fp32 slabs 33KiB unioned
//    with staging; per-chunk affine composite (Ac,Bc) computed IN the epilogue
//    from the fp16-rounded values -> chunk_compose kernel eliminated.
//  - bijective XCD swizzle: each XCD owns 32 m-tiles x all 8 e-tiles, e fastest
//    -> x m-tile fetched ~once from HBM (was ~4x, FETCH 532MB).
//  - plain fp16 GEMM (one mfma_f32_16x16x32_f16 per output per K-step).
//  - B k-chunk XOR swizzle on both sides (global source + ds_read addr).
// ws layout: Wg fp16 2M | Wh fp16 2M | (2 spare) | g fp16 64MiB | c fp16 64MiB
//            | Ac 4M | Bc 4M | Hst 4M

using u16   = unsigned short;
using f32x4 = __attribute__((ext_vector_type(4))) float;
using h16x4 = __attribute__((ext_vector_type(4))) _Float16;
using h16x8 = __attribute__((ext_vector_type(8))) _Float16;

#define M_TOTAL 32768
#define K_DIM   1024
#define E_DIM   1024
#define LCH     32     // scan chunk length
#define NCH     128    // chunks per sequence (4096/32)

// ---------------- W pre-convert: fp32 -> fp16 (RTNE) ----------------
__global__ void conv_w(const float* __restrict__ wg, const float* __restrict__ wh,
                       u16* __restrict__ dst_base, int n4) {
    const float* w = blockIdx.y ? wh : wg;
    u16* dst = dst_base + (size_t)blockIdx.y * 1024 * 1024;  // elements
    int i = blockIdx.x * blockDim.x + threadIdx.x;
    if (i >= n4) return;
    f32x4 f = ((const f32x4*)w)[i];
    h16x4 h;
#pragma unroll
    for (int c = 0; c < 4; ++c) h[c] = (_Float16)f[c];
    ((h16x4*)dst)[i] = h;
}

__device__ inline float fast_sigmoid(float z) {
    return 1.f / (1.f + __expf(-z));
}
__device__ inline float fast_tanh(float z) {
    return 1.f - 2.f / (__expf(2.f * z) + 1.f);  // saturates correctly
}

// ---------------- GEMM + activation + per-chunk composite ----------------
// 1D grid of 2048 blocks, XCD-swizzled; 512 threads.
__global__ __launch_bounds__(512, 4) void gemm_act(
    const float* __restrict__ x,
    const u16* __restrict__ wg_h, const u16* __restrict__ wh_h,
    const float* __restrict__ bg, const float* __restrict__ bh,
    _Float16* __restrict__ g_out, _Float16* __restrict__ c_out,
    float* __restrict__ Ac, float* __restrict__ Bc) {

    // XCD decode: dispatch round-robins bid across 8 XCDs. Give XCD x the
    // m-tiles [32x, 32x+32), e fastest -> the 8 blocks sharing an x m-tile are
    // temporally adjacent ON THE SAME XCD (L2 reuse of x).
    const int bid   = blockIdx.x;
    const int xcd   = bid & 7;
    const int local = bid >> 3;              // 0..255
    const int mt    = xcd * 32 + (local >> 3);
    const int et    = local & 7;
    const int e0    = et * 128;
    const int m0    = mt * 128;

    // Staging unioned with the epilogue slabs (one 32-row chunk of g and c in
    // fp32). A padded stride 40 (2-way bank alias, free). B rows unpadded 64B
    // (lds-dma requirement); k-chunk XOR swizzle breaks its conflict.
    __shared__ __align__(16) union SM {
        struct {
            u16 A[128 * 40];    // x tile as fp16, padded stride 40
            u16 B[2][128 * 32]; // Wg, Wh fp16 (unpadded for lds-dma)
        } s;
        struct {
            float g[32][132];
            float c[32][132];
        } ep;
    } sm;

    const int tid  = threadIdx.x;
    const int lane = tid & 63;
    const int wave = tid >> 6;                // 0..7
    const int wr = wave >> 2, wc = wave & 3;  // 2x4 wave grid, wave tile 64x32
    const int lr = lane & 15;                 // row/col within 16
    const int kg = lane >> 4;                 // k-group (quad)

    const u16* __restrict__ Wptr[2] = {wg_h, wh_h};

    f32x4 accg[4][2], acch[4][2];
#pragma unroll
    for (int tr = 0; tr < 4; ++tr)
#pragma unroll
        for (int tc = 0; tc < 2; ++tc) {
            accg[tr][tc] = (f32x4){0.f, 0.f, 0.f, 0.f};
            acch[tr][tc] = (f32x4){0.f, 0.f, 0.f, 0.f};
        }

    for (int kt = 0; kt < K_DIM / 32; ++kt) {
        __syncthreads();  // previous iter's LDS reads done before overwrite

        // ---- stage B (2 weight regions) via async global->LDS, 16B chunks ----
        // Source k-chunk XOR-swizzled per row; LDS destination linear.
#pragma unroll
        for (int rgn = 0; rgn < 2; ++rgn) {
            int ch  = tid;                    // 512 chunks of 16B = 8KB
            int row = ch >> 2;                // e-row 0..127
            int kq  = ch & 3;                 // 16B k-chunk slot
            int kqs = kq ^ ((row >> 1) & 3);  // source chunk (involution)
            size_t goff = (size_t)(e0 + row) * K_DIM + kt * 32 + kqs * 8;
            __builtin_amdgcn_global_load_lds(
                (const __attribute__((address_space(1))) void*)(Wptr[rgn] + goff),
                (__attribute__((address_space(3))) void*)(&sm.s.B[rgn][ch * 8]), 16, 0, 0);
        }

        // ---- stage A (x rows), convert fp32 -> fp16 ----
#pragma unroll
        for (int j = 0; j < 2; ++j) {
            int q   = tid + 512 * j;          // 1024 float4s = 128x32 fp32
            int row = q >> 3;                 // m-row 0..127
            int kq  = q & 7;                  // float4 within row
            f32x4 f = *(const f32x4*)(x + (size_t)(m0 + row) * K_DIM + kt * 32 + kq * 4);
            h16x4 h;
#pragma unroll
            for (int c = 0; c < 4; ++c) h[c] = (_Float16)f[c];
            *(h16x4*)&sm.s.A[row * 40 + kq * 4] = h;
        }

        __syncthreads();

        // ---- fragments + MFMA (A frags shared across both GEMMs) ----
        h16x8 ah[4];
#pragma unroll
        for (int tr = 0; tr < 4; ++tr) {
            int r = wr * 64 + tr * 16 + lr;
            ah[tr] = *(const h16x8*)&sm.s.A[r * 40 + kg * 8];
        }
#pragma unroll
        for (int tc = 0; tc < 2; ++tc) {
            int e   = wc * 32 + tc * 16 + lr;
            int kgs = kg ^ ((e >> 1) & 3);    // swizzled slot holding chunk kg
            h16x8 bgv = *(const h16x8*)&sm.s.B[0][e * 32 + kgs * 8];
            h16x8 bhv = *(const h16x8*)&sm.s.B[1][e * 32 + kgs * 8];
#pragma unroll
            for (int tr = 0; tr < 4; ++tr) {
                accg[tr][tc] = __builtin_amdgcn_mfma_f32_16x16x32_f16(ah[tr], bgv, accg[tr][tc], 0, 0, 0);
                acch[tr][tc] = __builtin_amdgcn_mfma_f32_16x16x32_f16(ah[tr], bhv, acch[tr][tc], 0, 0, 0);
            }
        }
    }

    // ---- epilogue: 4 slabs of 32 rows (= 1 scan chunk each) ----
    // Per slab: fill g,c fp32 slabs -> coalesced fp16x8 stores -> in-LDS
    // serial composite over the 32 rows -> write Ac/Bc.
    float bgv[2], bhv[2];
#pragma unroll
    for (int tc = 0; tc < 2; ++tc) {
        int el = e0 + wc * 32 + tc * 16 + lr;
        bgv[tc] = bg[el];
        bhv[tc] = bh[el];
    }

#pragma unroll
    for (int s = 0; s < 4; ++s) {
        __syncthreads();  // staging / previous slab reads complete
        if (wr == (s >> 1)) {                 // 4 of 8 waves hold this slab
#pragma unroll
            for (int half = 0; half < 2; ++half) {
                int tr = (s & 1) * 2 + half;
#pragma unroll
                for (int tc = 0; tc < 2; ++tc) {
                    int el = wc * 32 + tc * 16 + lr;
#pragma unroll
                    for (int i = 0; i < 4; ++i) {
                        int row = half * 16 + kg * 4 + i;   // 0..31 in slab
                        sm.ep.g[row][el] = fast_sigmoid(accg[tr][tc][i] + bgv[tc]);
                        sm.ep.c[row][el] = fast_tanh(acch[tr][tc][i] + bhv[tc]);
                    }
                }
            }
        }
        __syncthreads();

        // coalesced fp16 stores: one h16x8 per thread per array (512 = 32x16)
        {
            int row = tid >> 4;               // 0..31
            int c8  = (tid & 15) * 8;
            size_t gofs = (size_t)(m0 + s * 32 + row) * E_DIM + e0 + c8;
            f32x4 v0 = *(const f32x4*)&sm.ep.g[row][c8];
            f32x4 v1 = *(const f32x4*)&sm.ep.g[row][c8 + 4];
            h16x8 hv;
#pragma unroll
            for (int j = 0; j < 4; ++j) { hv[j] = (_Float16)v0[j]; hv[j + 4] = (_Float16)v1[j]; }
            *(h16x8*)(g_out + gofs) = hv;
            v0 = *(const f32x4*)&sm.ep.c[row][c8];
            v1 = *(const f32x4*)&sm.ep.c[row][c8 + 4];
#pragma unroll
            for (int j = 0; j < 4; ++j) { hv[j] = (_Float16)v0[j]; hv[j + 4] = (_Float16)v1[j]; }
            *(h16x8*)(c_out + gofs) = hv;
        }

        // per-chunk affine composite from the fp16-ROUNDED values (consistent
        // with what chunk_apply reads back). col = tid, 128 cols.
        if (tid < 128) {
            float A = 1.f, Bv = 0.f;
#pragma unroll 8
            for (int t = 0; t < LCH; ++t) {
                float g = (float)(_Float16)sm.ep.g[t][tid];
                float c = (float)(_Float16)sm.ep.c[t][tid];
                A  = g * A;
                Bv = g * Bv + (1.f - g) * c;
            }
            int m_abs = m0 + s * 32;
            int b  = m_abs >> 12;             // / 4096
            int ch = (m_abs & 4095) >> 5;     // chunk within sequence
            size_t o = ((size_t)b * NCH + ch) * 1024 + e0 + tid;
            Ac[o] = A;
            Bc[o] = Bv;
        }
    }
}

// ---------------- scan pass 2: prefix over chunks -> h at chunk entry ----------------
// 32 blocks x 256 threads = B*D threads; loads pipelined via unroll
__global__ void chunk_prefix(const float* __restrict__ Ac, const float* __restrict__ Bc,
                             const float* __restrict__ hidden, float* __restrict__ Hst) {
    int idx = blockIdx.x * 256 + threadIdx.x;   // 0..8191
    int b = idx >> 10;
    int d = idx & 1023;
    float h = hidden[b * 1024 + d];
#pragma unroll 8
    for (int ch = 0; ch < NCH; ++ch) {
        size_t o = ((size_t)b * NCH + ch) * 1024 + d;
        float A = Ac[o], Bv = Bc[o];
        Hst[o] = h;
        h = A * h + Bv;
    }
}

// ---------------- scan pass 3: apply ----------------
// grid (NCH, B), 256 threads, 4 channels per thread
__global__ void chunk_apply(const _Float16* __restrict__ g_arr,
                            const _Float16* __restrict__ c_arr,
                            const float* __restrict__ Hst,
                            float* __restrict__ out) {
    int d4 = threadIdx.x * 4;
    int ch = blockIdx.x;
    int b  = blockIdx.y;
    size_t base = ((size_t)b * 4096 + (size_t)ch * LCH) * 1024 + d4;
    size_t ho = ((size_t)b * NCH + ch) * 1024 + d4;
    f32x4 hv = *(const f32x4*)(Hst + ho);
    float h[4] = {hv[0], hv[1], hv[2], hv[3]};
#pragma unroll 4
    for (int t = 0; t < LCH; ++t) {
        size_t idx = base + (size_t)t * 1024;
        h16x4 gv = *(const h16x4*)(g_arr + idx);
        h16x4 cv = *(const h16x4*)(c_arr + idx);
#pragma unroll
        for (int j = 0; j < 4; ++j) {
            float g = (float)gv[j];
            float c = (float)cv[j];
            h[j] = g * h[j] + (1.f - g) * c;
        }
        *(f32x4*)(out + idx) = (f32x4){h[0], h[1], h[2], h[3]};
    }
}

extern "C" void kernel_launch(void* const* d_in, const int* in_sizes, int n_in,
                              void* d_out, int out_size, void* d_ws, size_t ws_size,
                              hipStream_t stream) {
    const float* x      = (const float*)d_in[0];
    const float* hidden = (const float*)d_in[1];
    const float* Wg     = (const float*)d_in[2];
    const float* bg     = (const float*)d_in[3];
    const float* Wh     = (const float*)d_in[4];
    const float* bh     = (const float*)d_in[5];
    float* out = (float*)d_out;

    char* ws = (char*)d_ws;
    const size_t WSEG = 2u * 1024u * 1024u;            // 2MB per W (fp16)
    u16* wg_h = (u16*)(ws + 0 * WSEG);
    u16* wh_h = (u16*)(ws + 1 * WSEG);                 // segs 2,3 spare (keeps offsets)
    const size_t HBYTES = (size_t)M_TOTAL * E_DIM * 2; // 64 MiB per fp16 array
    _Float16* g_arr = (_Float16*)(ws + 4 * WSEG);
    _Float16* c_arr = (_Float16*)(ws + 4 * WSEG + HBYTES);
    const size_t SSEG = (size_t)8 * NCH * 1024 * 4;    // 4 MiB per scan array
    float* Ac  = (float*)(ws + 4 * WSEG + 2 * HBYTES);
    float* Bc  = (float*)(ws + 4 * WSEG + 2 * HBYTES + SSEG);
    float* Hst = (float*)(ws + 4 * WSEG + 2 * HBYTES + 2 * SSEG);

    // 1) convert weights to fp16 (grid.y picks Wg/Wh)
    conv_w<<<dim3(1024, 2), 256, 0, stream>>>(Wg, Wh, wg_h, (1024 * 1024) / 4);

    // 2) fused dual GEMM + activation + per-chunk composite (XCD-swizzled grid)
    gemm_act<<<dim3(2048), 512, 0, stream>>>(
        x, wg_h, wh_h, bg, bh, g_arr, c_arr, Ac, Bc);

    // 3) chunked scan (compose is fused into gemm_act epilogue)
    chunk_prefix<<<dim3(32), 256, 0, stream>>>(Ac, Bc, hidden, Hst);
    chunk_apply<<<dim3(NCH, 8), 256, 0, stream>>>(g_arr, c_arr, Hst, out);
}

// Round 4
// 458.081 us; speedup vs baseline: 1.1547x; 1.1547x over previous
//
#include <hip/hip_runtime.h>
#include <hip/hip_bf16.h>
#include <cstdint>

// MinGRU: g=sigmoid(xWg^T+bg), c=tanh(xWh^T+bh), h_t = g*h_{t-1} + (1-g)*c
// B=8, L=4096, D=1024.  M = B*L = 32768, K = E = 1024.
//
// R7 (from R6 post-mortem: LDS-BW + per-step vmcnt(0) drain were the wall):
//  - x->fp16 prepass (written into d_out, reused as scratch; chunk_apply
//    overwrites all of d_out at the end). gemm A-staging becomes pure DMA.
//  - K-loop: double-buffered, ALL staging via global_load_lds (3 per thread),
//    ONE __syncthreads per K-step. Prefetch tile t+1 issued before compute of
//    tile t -> the compiler's vmcnt(0)-before-barrier lands after ~1242cy of
//    MFMA, so the drain is ~free (T3 2-phase minimum schedule).
//  - A and B both stored as 64 lines x 128B (row-pairs), 16B-chunk XOR swizzle
//    c ^= (line&7), applied to the per-lane GLOBAL source (LDS dest linear,
//    gload_lds-compatible) and to the ds_read address. Frag reads verified
//    <=2-way per 16-lane phase -> conflict-free. Offsets kt-invariant, hoisted.
//  - 512 threads, 8 waves (2m x 4e), wave tile 64x32 per GEMM, acc 64 VGPR,
//    launch_bounds(512,4) -> 2 blocks/CU, 16 waves/CU.
//  - epilogue: 4x 32-row slabs, fused per-chunk scan composite (unchanged).
//  - chunk_apply: 128-thread blocks, h16x8 (16B/lane) loads.
// ws layout: Wg16 2M | Wh16 2M | (2M spare x2) | g fp16 64MiB | c fp16 64MiB
//            | Ac 4M | Bc 4M | Hst 4M   (x16 lives in d_out)

using u16   = unsigned short;
using f32x4 = __attribute__((ext_vector_type(4))) float;
using h16x4 = __attribute__((ext_vector_type(4))) _Float16;
using h16x8 = __attribute__((ext_vector_type(8))) _Float16;

#define M_TOTAL 32768
#define K_DIM   1024
#define E_DIM   1024
#define LCH     32     // scan chunk length
#define NCH     128    // chunks per sequence (4096/32)

// ---------------- prepass: x, Wg, Wh -> fp16 (RTNE) ----------------
__global__ void prep(const float* __restrict__ x,
                     const float* __restrict__ wg, const float* __restrict__ wh,
                     u16* __restrict__ x16, u16* __restrict__ wg16,
                     u16* __restrict__ wh16) {
    const size_t XQ = (size_t)M_TOTAL * K_DIM / 4;   // 8388608 quads
    const size_t WQ = (size_t)K_DIM * E_DIM / 4;     // 262144 quads
    size_t i = (size_t)blockIdx.x * 256 + threadIdx.x;
    const float* src;
    u16* dst;
    size_t j;
    if (i < XQ)           { src = x;  dst = x16;  j = i; }
    else if (i < XQ + WQ) { src = wg; dst = wg16; j = i - XQ; }
    else                  { src = wh; dst = wh16; j = i - XQ - WQ; }
    f32x4 f = ((const f32x4*)src)[j];
    h16x4 h;
#pragma unroll
    for (int c = 0; c < 4; ++c) h[c] = (_Float16)f[c];
    ((h16x4*)dst)[j] = h;
}

__device__ inline float fast_sigmoid(float z) {
    return 1.f / (1.f + __expf(-z));
}
__device__ inline float fast_tanh(float z) {
    return 1.f - 2.f / (__expf(2.f * z) + 1.f);  // saturates correctly
}

// ---------------- GEMM + activation + per-chunk composite ----------------
// 1D grid of 2048 blocks, XCD-swizzled; 512 threads.
__global__ __launch_bounds__(512, 4) void gemm_act(
    const u16* __restrict__ x16,
    const u16* __restrict__ wg_h, const u16* __restrict__ wh_h,
    const float* __restrict__ bg, const float* __restrict__ bh,
    _Float16* __restrict__ g_out, _Float16* __restrict__ c_out,
    float* __restrict__ Ac, float* __restrict__ Bc) {

    // XCD decode: each XCD owns 32 consecutive m-tiles, e fastest -> the 8
    // blocks sharing an x m-tile are temporally adjacent on one XCD (L2 reuse).
    const int bid   = blockIdx.x;
    const int xcd   = bid & 7;
    const int local = bid >> 3;              // 0..255
    const int mt    = xcd * 32 + (local >> 3);
    const int et    = local & 7;
    const int e0    = et * 128;
    const int m0    = mt * 128;

    // Double-buffered staging; each tile = A 8KB + B 2x8KB = 24KB.
    // Layout: 64 lines x 128B (line = row-pair), chunk slot c holds global
    // chunk c^(line&7)  -> conflict-free swizzled ds_reads, linear DMA dest.
    __shared__ __align__(16) union SM {
        struct {
            u16 A[512 * 8];       // 8KB
            u16 B[2][512 * 8];    // 16KB
        } buf[2];
        struct {
            float g[32][132];
            float c[32][132];
        } ep;
    } sm;

    const int tid  = threadIdx.x;
    const int lane = tid & 63;
    const int wave = tid >> 6;                // 0..7
    const int wr = wave >> 2, wc = wave & 3;  // 2x4 wave grid, wave tile 64x32
    const int lr = lane & 15;                 // row/col within 16
    const int kg = lane >> 4;                 // k-group (quad)

    // ---- per-thread staging source decode (kt-invariant part) ----
    // thread stages chunk ch=tid of each region: line p=ch>>3, slot c=ch&7,
    // logical chunk clog = c ^ (p&7): row = 2p + (clog>>2), kc = clog&3.
    const int sp   = tid >> 3;
    const int sc   = tid & 7;
    const int sclog = sc ^ (sp & 7);
    const int srow  = sp * 2 + (sclog >> 2);
    const int skc   = sclog & 3;
    const u16* aSrc = x16 + (size_t)(m0 + srow) * K_DIM + skc * 8;
    const u16* bgSrc = wg_h + (size_t)(e0 + srow) * K_DIM + skc * 8;
    const u16* bhSrc = wh_h + (size_t)(e0 + srow) * K_DIM + skc * 8;

    // ---- fragment LDS element-offsets (kt-invariant, hoisted) ----
    int aoff[4], boff[2];
#pragma unroll
    for (int tr = 0; tr < 4; ++tr) {
        int r = wr * 64 + tr * 16 + lr;
        int p = r >> 1;
        int c = (((r & 1) << 2) | kg) ^ (p & 7);
        aoff[tr] = p * 64 + c * 8;
    }
#pragma unroll
    for (int tc = 0; tc < 2; ++tc) {
        int e = wc * 32 + tc * 16 + lr;
        int p = e >> 1;
        int c = (((e & 1) << 2) | kg) ^ (p & 7);
        boff[tc] = p * 64 + c * 8;
    }

    f32x4 accg[4][2], acch[4][2];
#pragma unroll
    for (int tr = 0; tr < 4; ++tr)
#pragma unroll
        for (int tc = 0; tc < 2; ++tc) {
            accg[tr][tc] = (f32x4){0.f, 0.f, 0.f, 0.f};
            acch[tr][tc] = (f32x4){0.f, 0.f, 0.f, 0.f};
        }

#define STAGE(bi, kt)                                                          \
    do {                                                                       \
        size_t ko = (size_t)(kt) * 32;                                         \
        __builtin_amdgcn_global_load_lds(                                      \
            (const __attribute__((address_space(1))) void*)(aSrc + ko),        \
            (__attribute__((address_space(3))) void*)(&sm.buf[bi].A[tid * 8]), \
            16, 0, 0);                                                         \
        __builtin_amdgcn_global_load_lds(                                      \
            (const __attribute__((address_space(1))) void*)(bgSrc + ko),       \
            (__attribute__((address_space(3))) void*)(&sm.buf[bi].B[0][tid * 8]),\
            16, 0, 0);                                                         \
        __builtin_amdgcn_global_load_lds(                                      \
            (const __attribute__((address_space(1))) void*)(bhSrc + ko),       \
            (__attribute__((address_space(3))) void*)(&sm.buf[bi].B[1][tid * 8]),\
            16, 0, 0);                                                         \
    } while (0)

    // prologue: stage tile 0
    STAGE(0, 0);
    __syncthreads();          // vmcnt(0): one full-latency stall, once

    int cur = 0;
    for (int kt = 0; kt < K_DIM / 32; ++kt) {
        if (kt + 1 < K_DIM / 32) STAGE(cur ^ 1, kt + 1);   // async prefetch

        const u16* Ab  = sm.buf[cur].A;
        const u16* Bg  = sm.buf[cur].B[0];
        const u16* Bh  = sm.buf[cur].B[1];

        h16x8 ah[4];
#pragma unroll
        for (int tr = 0; tr < 4; ++tr)
            ah[tr] = *(const h16x8*)&Ab[aoff[tr]];
#pragma unroll
        for (int tc = 0; tc < 2; ++tc) {
            h16x8 bgv = *(const h16x8*)&Bg[boff[tc]];
            h16x8 bhv = *(const h16x8*)&Bh[boff[tc]];
#pragma unroll
            for (int tr = 0; tr < 4; ++tr) {
                accg[tr][tc] = __builtin_amdgcn_mfma_f32_16x16x32_f16(ah[tr], bgv, accg[tr][tc], 0, 0, 0);
                acch[tr][tc] = __builtin_amdgcn_mfma_f32_16x16x32_f16(ah[tr], bhv, acch[tr][tc], 0, 0, 0);
            }
        }

        __syncthreads();      // prefetch had the whole compute phase to land
        cur ^= 1;
    }
#undef STAGE

    // ---- epilogue: 4 slabs of 32 rows (= 1 scan chunk each) ----
    float bgv[2], bhv[2];
#pragma unroll
    for (int tc = 0; tc < 2; ++tc) {
        int el = e0 + wc * 32 + tc * 16 + lr;
        bgv[tc] = bg[el];
        bhv[tc] = bh[el];
    }

#pragma unroll
    for (int s = 0; s < 4; ++s) {
        __syncthreads();  // staging / previous slab reads complete
        if (wr == (s >> 1)) {                 // 4 of 8 waves hold this slab
#pragma unroll
            for (int half = 0; half < 2; ++half) {
                int tr = (s & 1) * 2 + half;
#pragma unroll
                for (int tc = 0; tc < 2; ++tc) {
                    int el = wc * 32 + tc * 16 + lr;
#pragma unroll
                    for (int i = 0; i < 4; ++i) {
                        int row = half * 16 + kg * 4 + i;   // 0..31 in slab
                        sm.ep.g[row][el] = fast_sigmoid(accg[tr][tc][i] + bgv[tc]);
                        sm.ep.c[row][el] = fast_tanh(acch[tr][tc][i] + bhv[tc]);
                    }
                }
            }
        }
        __syncthreads();

        // coalesced fp16 stores: one h16x8 per thread per array (512 = 32x16)
        {
            int row = tid >> 4;               // 0..31
            int c8  = (tid & 15) * 8;
            size_t gofs = (size_t)(m0 + s * 32 + row) * E_DIM + e0 + c8;
            f32x4 v0 = *(const f32x4*)&sm.ep.g[row][c8];
            f32x4 v1 = *(const f32x4*)&sm.ep.g[row][c8 + 4];
            h16x8 hv;
#pragma unroll
            for (int j = 0; j < 4; ++j) { hv[j] = (_Float16)v0[j]; hv[j + 4] = (_Float16)v1[j]; }
            *(h16x8*)(g_out + gofs) = hv;
            v0 = *(const f32x4*)&sm.ep.c[row][c8];
            v1 = *(const f32x4*)&sm.ep.c[row][c8 + 4];
#pragma unroll
            for (int j = 0; j < 4; ++j) { hv[j] = (_Float16)v0[j]; hv[j + 4] = (_Float16)v1[j]; }
            *(h16x8*)(c_out + gofs) = hv;
        }

        // per-chunk affine composite from the fp16-ROUNDED values (consistent
        // with what chunk_apply reads back). col = tid, 128 cols.
        if (tid < 128) {
            float A = 1.f, Bv = 0.f;
#pragma unroll 8
            for (int t = 0; t < LCH; ++t) {
                float g = (float)(_Float16)sm.ep.g[t][tid];
                float c = (float)(_Float16)sm.ep.c[t][tid];
                A  = g * A;
                Bv = g * Bv + (1.f - g) * c;
            }
            int m_abs = m0 + s * 32;
            int b  = m_abs >> 12;             // / 4096
            int ch = (m_abs & 4095) >> 5;     // chunk within sequence
            size_t o = ((size_t)b * NCH + ch) * 1024 + e0 + tid;
            Ac[o] = A;
            Bc[o] = Bv;
        }
    }
}

// ---------------- scan pass 2: prefix over chunks -> h at chunk entry ----------------
__global__ void chunk_prefix(const float* __restrict__ Ac, const float* __restrict__ Bc,
                             const float* __restrict__ hidden, float* __restrict__ Hst) {
    int idx = blockIdx.x * 256 + threadIdx.x;   // 0..8191
    int b = idx >> 10;
    int d = idx & 1023;
    float h = hidden[b * 1024 + d];
#pragma unroll 8
    for (int ch = 0; ch < NCH; ++ch) {
        size_t o = ((size_t)b * NCH + ch) * 1024 + d;
        float A = Ac[o], Bv = Bc[o];
        Hst[o] = h;
        h = A * h + Bv;
    }
}

// ---------------- scan pass 3: apply ----------------
// grid (NCH, B), 128 threads, 8 channels per thread (16B/lane loads)
__global__ void chunk_apply(const _Float16* __restrict__ g_arr,
                            const _Float16* __restrict__ c_arr,
                            const float* __restrict__ Hst,
                            float* __restrict__ out) {
    int d8 = threadIdx.x * 8;
    int ch = blockIdx.x;
    int b  = blockIdx.y;
    size_t base = ((size_t)b * 4096 + (size_t)ch * LCH) * 1024 + d8;
    size_t ho = ((size_t)b * NCH + ch) * 1024 + d8;
    f32x4 h0 = *(const f32x4*)(Hst + ho);
    f32x4 h1 = *(const f32x4*)(Hst + ho + 4);
    float h[8] = {h0[0], h0[1], h0[2], h0[3], h1[0], h1[1], h1[2], h1[3]};
#pragma unroll 4
    for (int t = 0; t < LCH; ++t) {
        size_t idx = base + (size_t)t * 1024;
        h16x8 gv = *(const h16x8*)(g_arr + idx);
        h16x8 cv = *(const h16x8*)(c_arr + idx);
#pragma unroll
        for (int j = 0; j < 8; ++j) {
            float g = (float)gv[j];
            float c = (float)cv[j];
            h[j] = g * h[j] + (1.f - g) * c;
        }
        *(f32x4*)(out + idx)     = (f32x4){h[0], h[1], h[2], h[3]};
        *(f32x4*)(out + idx + 4) = (f32x4){h[4], h[5], h[6], h[7]};
    }
}

extern "C" void kernel_launch(void* const* d_in, const int* in_sizes, int n_in,
                              void* d_out, int out_size, void* d_ws, size_t ws_size,
                              hipStream_t stream) {
    const float* x      = (const float*)d_in[0];
    const float* hidden = (const float*)d_in[1];
    const float* Wg     = (const float*)d_in[2];
    const float* bg     = (const float*)d_in[3];
    const float* Wh     = (const float*)d_in[4];
    const float* bh     = (const float*)d_in[5];
    float* out = (float*)d_out;

    char* ws = (char*)d_ws;
    const size_t WSEG = 2u * 1024u * 1024u;            // 2MB per W (fp16)
    u16* wg_h = (u16*)(ws + 0 * WSEG);
    u16* wh_h = (u16*)(ws + 1 * WSEG);                 // segs 2,3 spare
    const size_t HBYTES = (size_t)M_TOTAL * E_DIM * 2; // 64 MiB per fp16 array
    _Float16* g_arr = (_Float16*)(ws + 4 * WSEG);
    _Float16* c_arr = (_Float16*)(ws + 4 * WSEG + HBYTES);
    const size_t SSEG = (size_t)8 * NCH * 1024 * 4;    // 4 MiB per scan array
    float* Ac  = (float*)(ws + 4 * WSEG + 2 * HBYTES);
    float* Bc  = (float*)(ws + 4 * WSEG + 2 * HBYTES + SSEG);
    float* Hst = (float*)(ws + 4 * WSEG + 2 * HBYTES + 2 * SSEG);

    // x16 scratch lives in d_out (64MB of its 128MB); chunk_apply overwrites
    // all of d_out afterwards, so this is safe in stream order.
    u16* x16 = (u16*)d_out;

    // 1) convert x + weights to fp16
    const int XQ = M_TOTAL * (K_DIM / 4);              // 8388608
    const int WQ = K_DIM * (E_DIM / 4);                // 262144
    prep<<<dim3((XQ + 2 * WQ) / 256), 256, 0, stream>>>(x, Wg, Wh, x16, wg_h, wh_h);

    // 2) fused dual GEMM + activation + per-chunk composite (XCD-swizzled grid)
    gemm_act<<<dim3(2048), 512, 0, stream>>>(
        x16, wg_h, wh_h, bg, bh, g_arr, c_arr, Ac, Bc);

    // 3) chunked scan (compose fused into gemm_act epilogue)
    chunk_prefix<<<dim3(32), 256, 0, stream>>>(Ac, Bc, hidden, Hst);
    chunk_apply<<<dim3(NCH, 8), 128, 0, stream>>>(g_arr, c_arr, Hst, out);
}